// Round 6
// baseline (414.343 us; speedup 1.0000x reference)
//
#include <hip/hip_runtime.h>
#include <math.h>

typedef __attribute__((ext_vector_type(4))) float f32x4;
typedef __attribute__((ext_vector_type(8))) short short8;
typedef __attribute__((ext_vector_type(4))) short bf16x4;

__device__ __forceinline__ short f2bf(float f) {
    unsigned u = __builtin_bit_cast(unsigned, f);
    u += 0x7FFFu + ((u >> 16) & 1u);          // RNE (inputs finite)
    return (short)(u >> 16);
}
__device__ __forceinline__ float bf2f(short s) {
    unsigned u = ((unsigned)(unsigned short)s) << 16;
    return __builtin_bit_cast(float, u);
}
__device__ __forceinline__ short8 pack8(const float* x) {
    short8 r;
    #pragma unroll
    for (int i = 0; i < 8; ++i) r[i] = f2bf(x[i]);
    return r;
}
__device__ __forceinline__ void load16(const float* p, float* x) {
    const float4* q = (const float4*)p;
    #pragma unroll
    for (int i = 0; i < 4; ++i) {
        float4 v = q[i];
        x[i*4+0] = v.x; x[i*4+1] = v.y; x[i*4+2] = v.z; x[i*4+3] = v.w;
    }
}
__device__ __forceinline__ float fast_tanh(float x) {
    float cx = fminf(fmaxf(x, -9.f), 9.f);
    float e = __expf(2.f * cx);
    return (e - 1.f) / (e + 1.f);
}

// ---------------- weight transpose+convert: WT[n][k] bf16 <- W[k][n] f32 ----
__global__ __launch_bounds__(256) void convert_wt_k(
    const float* __restrict__ in_w, const float* __restrict__ ecapa_w,
    const float* __restrict__ att_w1, const float* __restrict__ att_w2,
    const float* __restrict__ arn_w1, const float* __restrict__ out_w,
    const float* __restrict__ gln_g, short* __restrict__ WT)
{
    int id = blockIdx.x * 256 + threadIdx.x;
    if (id < 81920) { int n = id / 320, k = id - n * 320; WT[id] = f2bf(in_w[k * 256 + n]); return; }
    id -= 81920;
    if (id < 65536) { int n = id >> 8, k = id & 255; WT[81920 + (n << 8) + k] = f2bf(gln_g[k] * ecapa_w[k * 256 + n]); return; }
    id -= 65536;
    if (id < 65536) { int n = id >> 8, k = id & 255; WT[147456 + (n << 8) + k] = f2bf(att_w1[k * 256 + n]); return; }
    id -= 65536;
    if (id < 65536) { int n = id >> 8, k = id & 255; WT[212992 + (n << 8) + k] = f2bf(att_w2[k * 256 + n]); return; }
    id -= 65536;
    if (id < 262144) {
        int i = id >> 16, r = id & 65535, n = r >> 8, k = r & 255;
        WT[278528 + id] = f2bf(arn_w1[i * 65536 + k * 256 + n]); return;
    }
    id -= 262144;
    if (id < 98304) {
        int n = id >> 8, k = id & 255;
        WT[540672 + id] = (n < 320) ? f2bf(out_w[k * 320 + n]) : (short)0; return;
    }
}

// u[n] = sum_k g[k] W[k][n] ; v[n] = sum_k gb[k] W[k][n] + ecapa_b[n]
__global__ __launch_bounds__(256) void glnuv_k(const float* __restrict__ ecapa_w,
    const float* __restrict__ gln_g, const float* __restrict__ gln_b,
    const float* __restrict__ ecapa_b, float* __restrict__ uArr, float* __restrict__ vArr)
{
    int n = threadIdx.x;
    float u = 0.f, v = 0.f;
    #pragma unroll 8
    for (int k = 0; k < 256; ++k) {
        float w = ecapa_w[k * 256 + n];
        u = fmaf(gln_g[k], w, u);
        v = fmaf(gln_b[k], w, v);
    }
    uArr[n] = u;
    vArr[n] = v + ecapa_b[n];
}

// ---------------- bf16 MFMA GEMM (swapped-operand C layout) ----------------
// C-frag per lane (fr,fc): row = m0+wm*64+fr*16+(lane&15),
//                          cols = n0+wn*64+fc*16+(lane>>4)*4 + 0..3
template<int AMODE, int EPI, int TPB, int OUTBF>
__global__ __launch_bounds__(256) void mfma_gemm_k(
    const float* __restrict__ Asrc, const short* __restrict__ WT,
    const float* __restrict__ bias, void* __restrict__ Cv,
    const float* __restrict__ rowvec,
    const float* __restrict__ ng0, const float* __restrict__ ng1,
    const float* __restrict__ stat0, const float* __restrict__ stat1,
    const int* __restrict__ lens,
    int K, int N, int Lsig)
{
    __shared__ short As[128 * 32];
    __shared__ short Bs[128 * 32];
    const int tid = threadIdx.x;
    const int n0 = blockIdx.x * 128, m0 = blockIdx.y * 128;
    const int rl = tid >> 1, kh = tid & 1;
    const int lane = tid & 63, w = tid >> 6;
    const int wm = w >> 1, wn = w & 1;
    const int lr = lane & 15, ls = lane >> 4;

    const int arow = m0 + rl;
    const float* aptr;
    int tt = 0;
    if (AMODE == 0) {
        aptr = Asrc + (long)arow * K;
    } else {
        int b = arow / TPB; tt = arow - b * TPB;
        aptr = Asrc + (long)b * Lsig + 160 * tt;
    }
    const short* bsrc = WT + (long)(n0 + rl) * K;

    const int s0 = (2 * kh) ^ (rl & 3), s1 = (2 * kh + 1) ^ (rl & 3);
    short* aw0 = &As[rl * 32 + s0 * 8]; short* aw1 = &As[rl * 32 + s1 * 8];
    short* bw0 = &Bs[rl * 32 + s0 * 8]; short* bw1 = &Bs[rl * 32 + s1 * 8];
    const int rco = (ls ^ (lr & 3)) * 8;

    f32x4 acc[4][4] = {};
    float x[16];
    short8 blo, bhi;

    {
        const int kk = kh * 16;
        if (AMODE == 0) {
            load16(aptr + kk, x);
        } else {
            int base = 160 * tt + kk;
            if (base + 15 < Lsig) load16(aptr + kk, x);
            else {
                #pragma unroll
                for (int e = 0; e < 16; ++e) x[e] = (base + e < Lsig) ? aptr[kk + e] : 0.f;
            }
        }
        blo = *(const short8*)(bsrc + kk);
        bhi = *(const short8*)(bsrc + kk + 8);
    }

    for (int k0 = 0; k0 < K; k0 += 32) {
        *(short8*)aw0 = pack8(x);
        *(short8*)aw1 = pack8(x + 8);
        *(short8*)bw0 = blo;
        *(short8*)bw1 = bhi;
        __syncthreads();
        if (k0 + 32 < K) {
            const int kk = k0 + 32 + kh * 16;
            if (AMODE == 0) {
                load16(aptr + kk, x);
            } else {
                int base = 160 * tt + kk;
                if (base + 15 < Lsig) load16(aptr + kk, x);
                else {
                    #pragma unroll
                    for (int e = 0; e < 16; ++e) x[e] = (base + e < Lsig) ? aptr[kk + e] : 0.f;
                }
            }
            blo = *(const short8*)(bsrc + kk);
            bhi = *(const short8*)(bsrc + kk + 8);
        }
        short8 af[4], bfr[4];
        #pragma unroll
        for (int f = 0; f < 4; ++f) {
            af[f]  = *(const short8*)&As[(wm * 64 + f * 16 + lr) * 32 + rco];
            bfr[f] = *(const short8*)&Bs[(wn * 64 + f * 16 + lr) * 32 + rco];
        }
        #pragma unroll
        for (int fr = 0; fr < 4; ++fr)
            #pragma unroll
            for (int fc = 0; fc < 4; ++fc)
                acc[fr][fc] = __builtin_amdgcn_mfma_f32_16x16x32_bf16(bfr[fc], af[fr], acc[fr][fc], 0, 0, 0);
        __syncthreads();
    }

    #pragma unroll
    for (int fr = 0; fr < 4; ++fr) {
        const int row = m0 + wm * 64 + fr * 16 + lr;
        int bb = 0, tloc = 0;
        if (EPI != 0) { bb = row / TPB; tloc = row - bb * TPB; }
        float mean = 0.f, rstd = 0.f; int lenb = 0;
        if (EPI == 5) { mean = stat0[bb]; rstd = stat1[bb]; lenb = lens[bb]; }
        #pragma unroll
        for (int fc = 0; fc < 4; ++fc) {
            const int col = n0 + wn * 64 + fc * 16 + ls * 4;
            if (col >= N) continue;
            f32x4 a = acc[fr][fc];
            float4 r;
            if (EPI == 0) {
                float4 bv = *(const float4*)(bias + col);
                r.x = a[0] + bv.x; r.y = a[1] + bv.y; r.z = a[2] + bv.z; r.w = a[3] + bv.w;
            } else if (EPI == 2) {
                float4 rvv = *(const float4*)(rowvec + bb * 256 + col);
                float4 g0 = *(const float4*)(ng0 + col);
                float4 g1 = *(const float4*)(ng1 + col);
                r.x = fast_tanh(fmaxf(a[0] + rvv.x, 0.f) * g0.x + g1.x);
                r.y = fast_tanh(fmaxf(a[1] + rvv.y, 0.f) * g0.y + g1.y);
                r.z = fast_tanh(fmaxf(a[2] + rvv.z, 0.f) * g0.z + g1.z);
                r.w = fast_tanh(fmaxf(a[3] + rvv.w, 0.f) * g0.w + g1.w);
            } else { // EPI 5
                float4 uu = *(const float4*)(ng0 + col);
                float4 vv = *(const float4*)(ng1 + col);
                bool val = tloc < lenb;
                r.x = val ? fmaxf(rstd * (a[0] - mean * uu.x) + vv.x, 0.f) : 0.f;
                r.y = val ? fmaxf(rstd * (a[1] - mean * uu.y) + vv.y, 0.f) : 0.f;
                r.z = val ? fmaxf(rstd * (a[2] - mean * uu.z) + vv.z, 0.f) : 0.f;
                r.w = val ? fmaxf(rstd * (a[3] - mean * uu.w) + vv.w, 0.f) : 0.f;
            }
            if (OUTBF) {
                bf16x4 o; o[0] = f2bf(r.x); o[1] = f2bf(r.y); o[2] = f2bf(r.z); o[3] = f2bf(r.w);
                *(bf16x4*)((short*)Cv + (long)row * N + col) = o;
            } else {
                *(float4*)((float*)Cv + (long)row * N + col) = r;
            }
        }
    }
}

// ------ fused 4x ARN + out_w projection, v2 ------
// 64-row tile, 512 thr = 8 waves (2 wm x 4 wn), SINGLE 32KB LDS buffer with
// read-phase/barrier/write-phase/barrier per layer. 2 blocks/CU (launch_bounds).
__global__ __launch_bounds__(512, 4) void arn_fused_k(
    const short* __restrict__ o0b, const short* __restrict__ WT_arn,
    const short* __restrict__ WT_out, const float* __restrict__ out_b,
    const float* __restrict__ arnvec, float* __restrict__ y)
{
    __shared__ short Tb[64 * 256];
    const int tid = threadIdx.x;
    const int m0 = blockIdx.x * 64;
    const int lane = tid & 63, w = tid >> 6;
    const int wm = w >> 2, wn = w & 3;
    const int lr = lane & 15, ls = lane >> 4;

    // stage 64x256 bf16 tile (swizzled slots)
    {
        int row = tid >> 3, q = (tid & 7) * 4;
        const short* src = o0b + (long)(m0 + row) * 256 + q * 8;
        #pragma unroll
        for (int s = 0; s < 4; ++s) {
            short8 v = *(const short8*)(src + s * 8);
            int slot = q + s;
            *(short8*)&Tb[row * 256 + ((slot ^ (row & 7)) << 3)] = v;
        }
    }
    __syncthreads();

    // residual init (bf16-rounded o0)
    f32x4 r[2][4];
    #pragma unroll
    for (int fr = 0; fr < 2; ++fr) {
        int row = wm * 32 + fr * 16 + lr;
        #pragma unroll
        for (int fc = 0; fc < 4; ++fc) {
            int col = wn * 64 + fc * 16 + ls * 4;
            int slot = col >> 3, off = col & 7;
            bf16x4 v = *(const bf16x4*)&Tb[row * 256 + ((slot ^ (row & 7)) << 3) + off];
            r[fr][fc][0] = bf2f(v[0]); r[fr][fc][1] = bf2f(v[1]);
            r[fr][fc][2] = bf2f(v[2]); r[fr][fc][3] = bf2f(v[3]);
        }
    }

    for (int i = 0; i < 4; ++i) {
        const short* Wl = WT_arn + (long)i * 65536;
        const float* rv = arnvec + (long)i * 8192;
        f32x4 acc[2][4] = {};
        // ---- read phase: consume Tb ----
        #pragma unroll
        for (int ks = 0; ks < 8; ++ks) {
            short8 af[2], bq[4];
            #pragma unroll
            for (int fr = 0; fr < 2; ++fr) {
                int row = wm * 32 + fr * 16 + lr;
                int slot = ks * 4 + ls;
                af[fr] = *(const short8*)&Tb[row * 256 + ((slot ^ (row & 7)) << 3)];
            }
            #pragma unroll
            for (int fc = 0; fc < 4; ++fc) {
                int n = wn * 64 + fc * 16 + lr;
                bq[fc] = *(const short8*)(Wl + n * 256 + ks * 32 + ls * 8);
            }
            #pragma unroll
            for (int fr = 0; fr < 2; ++fr)
                #pragma unroll
                for (int fc = 0; fc < 4; ++fc)
                    acc[fr][fc] = __builtin_amdgcn_mfma_f32_16x16x32_bf16(bq[fc], af[fr], acc[fr][fc], 0, 0, 0);
        }
        __syncthreads();   // all reads of Tb complete
        // ---- write phase: residual update + write own (rows, cols) region ----
        #pragma unroll
        for (int fr = 0; fr < 2; ++fr) {
            int rowl = wm * 32 + fr * 16 + lr;
            int bb = (m0 + rowl) / 1000;
            #pragma unroll
            for (int fc = 0; fc < 4; ++fc) {
                int col = wn * 64 + fc * 16 + ls * 4;
                float4 rvv = *(const float4*)(rv + bb * 256 + col);
                f32x4 a = acc[fr][fc];
                r[fr][fc][0] += fast_tanh(a[0] + rvv.x);
                r[fr][fc][1] += fast_tanh(a[1] + rvv.y);
                r[fr][fc][2] += fast_tanh(a[2] + rvv.z);
                r[fr][fc][3] += fast_tanh(a[3] + rvv.w);
                bf16x4 o;
                o[0] = f2bf(r[fr][fc][0]); o[1] = f2bf(r[fr][fc][1]);
                o[2] = f2bf(r[fr][fc][2]); o[3] = f2bf(r[fr][fc][3]);
                int slot = col >> 3, off = col & 7;
                *(bf16x4*)&Tb[rowl * 256 + ((slot ^ (rowl & 7)) << 3) + off] = o;
            }
        }
        __syncthreads();   // writes visible before next layer's reads
    }

    // projection: y[64][320] = Tb @ out_wT + out_b  (wave covers cols wn*80..+80)
    f32x4 pacc[2][5] = {};
    #pragma unroll
    for (int ks = 0; ks < 8; ++ks) {
        short8 af[2];
        #pragma unroll
        for (int fr = 0; fr < 2; ++fr) {
            int row = wm * 32 + fr * 16 + lr;
            int slot = ks * 4 + ls;
            af[fr] = *(const short8*)&Tb[row * 256 + ((slot ^ (row & 7)) << 3)];
        }
        #pragma unroll
        for (int fc = 0; fc < 5; ++fc) {
            int n = wn * 80 + fc * 16 + lr;
            short8 bq = *(const short8*)(WT_out + n * 256 + ks * 32 + ls * 8);
            #pragma unroll
            for (int fr = 0; fr < 2; ++fr)
                pacc[fr][fc] = __builtin_amdgcn_mfma_f32_16x16x32_bf16(bq, af[fr], pacc[fr][fc], 0, 0, 0);
        }
    }
    #pragma unroll
    for (int fc = 0; fc < 5; ++fc) {
        #pragma unroll
        for (int fr = 0; fr < 2; ++fr) {
            int row = m0 + wm * 32 + fr * 16 + lr;
            int cb = wn * 80 + fc * 16 + ls * 4;
            float4 ob = *(const float4*)(out_b + cb);
            f32x4 a = pacc[fr][fc];
            float4 o;
            o.x = a[0] + ob.x; o.y = a[1] + ob.y; o.z = a[2] + ob.z; o.w = a[3] + ob.w;
            *(float4*)(y + (long)row * 320 + cb) = o;
        }
    }
}

// ------------- GLN stats, phase 1 -------
__global__ __launch_bounds__(256) void gln_part_k(const float* __restrict__ aux,
    const int* __restrict__ lens, float* __restrict__ part)
{
    int b = blockIdx.x, p = blockIdx.y, tid = threadIdx.x;
    int len = lens[b];
    int t0 = p * 25, t1 = min(len, t0 + 25);
    const float4* src = (const float4*)(aux + (long)b * 400 * 256);
    float s = 0.f, ss = 0.f;
    for (int i = t0 * 64 + tid; i < t1 * 64; i += 256) {
        float4 v = src[i];
        s += v.x + v.y + v.z + v.w;
        ss += v.x*v.x + v.y*v.y + v.z*v.z + v.w*v.w;
    }
    for (int off = 32; off; off >>= 1) { s += __shfl_down(s, off); ss += __shfl_down(ss, off); }
    __shared__ float l1[4], l2[4];
    if ((tid & 63) == 0) { l1[tid >> 6] = s; l2[tid >> 6] = ss; }
    __syncthreads();
    if (tid == 0) {
        part[b * 16 + p]       = l1[0] + l1[1] + l1[2] + l1[3];
        part[512 + b * 16 + p] = l2[0] + l2[1] + l2[2] + l2[3];
    }
}

// ------------- GLN stats, phase 2 -------
__global__ __launch_bounds__(512) void gln_comb_k(const float* __restrict__ part,
    const int* __restrict__ lens, float* __restrict__ meanA, float* __restrict__ rstdA)
{
    __shared__ float s1[32][16], s2[32][16];
    int tid = threadIdx.x, b = tid >> 4, p = tid & 15;
    s1[b][p] = part[b * 16 + p];
    s2[b][p] = part[512 + b * 16 + p];
    __syncthreads();
    if (tid < 32) {
        float s = 0.f, ss = 0.f;
        for (int q = 0; q < 16; ++q) { s += s1[tid][q]; ss += s2[tid][q]; }
        float cnt = (float)lens[tid] * 256.f;
        float mean = s / cnt;
        float var = ss / cnt - mean * mean;
        meanA[tid] = mean;
        rstdA[tid] = 1.0f / sqrtf(var + 1e-5f);
    }
}

// ------------- time stats, phase 1 -------
__global__ __launch_bounds__(256) void stats_part_k(const float* __restrict__ h,
    const int* __restrict__ lens, float* __restrict__ part)
{
    int b = blockIdx.x, p = blockIdx.y, c = threadIdx.x;
    int len = lens[b];
    int t0 = p * 50, t1 = min(len, t0 + 50);
    const float* hp = h + ((long)b * 400 + t0) * 256 + c;
    float s = 0.f, ss = 0.f;
    for (int t = 0; t < t1 - t0; ++t) { float v = hp[(long)t * 256]; s += v; ss = fmaf(v, v, ss); }
    part[((long)b * 8 + p) * 256 + c] = s;
    part[65536 + ((long)b * 8 + p) * 256 + c] = ss;
}

// ------------- time stats, phase 2 -------
__global__ __launch_bounds__(256) void stats_comb_k(const float* __restrict__ part,
    const int* __restrict__ lens, const float* __restrict__ att_w1,
    const float* __restrict__ att_b1, float* __restrict__ attbias)
{
    int b = blockIdx.x, c = threadIdx.x;
    float s = 0.f, ss = 0.f;
    #pragma unroll
    for (int p = 0; p < 8; ++p) {
        s += part[((long)b * 8 + p) * 256 + c];
        ss += part[65536 + ((long)b * 8 + p) * 256 + c];
    }
    float n = (float)lens[b];
    float m = s / n;
    float var = (ss - n * m * m) / (n - 1.0f);
    float sd = sqrtf(fmaxf(var, 1e-4f));
    __shared__ float mS[256], sS[256];
    mS[c] = m; sS[c] = sd;
    __syncthreads();
    float a0 = att_b1[c], a1 = 0.f;
    #pragma unroll 4
    for (int k = 0; k < 256; ++k) {
        a0 = fmaf(mS[k], att_w1[(256 + k) * 256 + c], a0);
        a1 = fmaf(sS[k], att_w1[(512 + k) * 256 + c], a1);
    }
    attbias[b * 256 + c] = a0 + a1;
}

// ------------- softmax-pool, phase 1 -------
__global__ __launch_bounds__(256) void softmax_part_k(const float* __restrict__ logits,
    const float* __restrict__ h, const int* __restrict__ lens, float* __restrict__ part)
{
    int b = blockIdx.x, p = blockIdx.y, c = threadIdx.x;
    int len = lens[b];
    int t0 = p * 50, t1 = min(len, t0 + 50);
    int nt = t1 - t0;
    const float* lp = logits + ((long)b * 400 + t0) * 256 + c;
    const float* hp = h + ((long)b * 400 + t0) * 256 + c;
    float mx = -1e30f;
    for (int t = 0; t < nt; ++t) mx = fmaxf(mx, lp[(long)t * 256]);
    float den = 0.f, mu = 0.f, m2 = 0.f;
    for (int t = 0; t < nt; ++t) {
        float e = __expf(lp[(long)t * 256] - mx);
        float hv = hp[(long)t * 256];
        den += e;
        mu = fmaf(e, hv, mu);
        m2 = fmaf(e * hv, hv, m2);
    }
    long o = ((long)b * 8 + p) * 256 + c;
    part[o] = mx; part[o + 65536] = den; part[o + 131072] = mu; part[o + 196608] = m2;
}

// ------------- softmax-pool, phase 2 -------
__global__ __launch_bounds__(256) void softmax_comb_k(const float* __restrict__ part,
    const float* __restrict__ bn5g, const float* __restrict__ bn5b, float* __restrict__ e5)
{
    int b = blockIdx.x, c = threadIdx.x;
    float mx[8], M = -1e30f;
    #pragma unroll
    for (int p = 0; p < 8; ++p) { mx[p] = part[((long)b * 8 + p) * 256 + c]; M = fmaxf(M, mx[p]); }
    float den = 0.f, mu = 0.f, m2 = 0.f;
    #pragma unroll
    for (int p = 0; p < 8; ++p) {
        long o = ((long)b * 8 + p) * 256 + c;
        float sc = __expf(mx[p] - M);
        den = fmaf(part[o + 65536], sc, den);
        mu  = fmaf(part[o + 131072], sc, mu);
        m2  = fmaf(part[o + 196608], sc, m2);
    }
    mu /= den; m2 /= den;
    float sg = sqrtf(fmaxf(m2 - mu * mu, 1e-4f));
    e5[b * 512 + c]       = mu * bn5g[c] + bn5b[c];
    e5[b * 512 + 256 + c] = sg * bn5g[256 + c] + bn5b[256 + c];
}

// -------- fc6+bn6 -> emb(embG) ; L2-norm -> classify --------
__global__ __launch_bounds__(1024) void emb_k(const float* __restrict__ e5,
    const float* __restrict__ fc6w, const float* __restrict__ fc6b,
    const float* __restrict__ bn6g, const float* __restrict__ bn6b,
    const float* __restrict__ clsw, const float* __restrict__ clsb,
    float* __restrict__ classify, float* __restrict__ embG)
{
    int b = blockIdx.x, tid = threadIdx.x;
    int g = tid >> 8, c = tid & 255;
    __shared__ float es[512], embS[256], fP[4][256], red[4], cP[8][128];
    __shared__ float invS;
    if (tid < 512) es[tid] = e5[b * 512 + tid];
    __syncthreads();
    float acc = 0.f;
    for (int k = g * 128; k < g * 128 + 128; ++k)
        acc = fmaf(es[k], fc6w[k * 256 + c], acc);
    fP[g][c] = acc;
    __syncthreads();
    if (g == 0) {
        float e = fP[0][c] + fP[1][c] + fP[2][c] + fP[3][c] + fc6b[c];
        float eb = e * bn6g[c] + bn6b[c];
        embS[c] = eb;
        embG[b * 256 + c] = eb;
    }
    __syncthreads();
    if (tid < 256) {
        float sq = embS[tid] * embS[tid];
        for (int off = 32; off; off >>= 1) sq += __shfl_down(sq, off);
        if ((tid & 63) == 0) red[tid >> 6] = sq;
    }
    __syncthreads();
    if (tid == 0) invS = 1.0f / fmaxf(sqrtf(red[0] + red[1] + red[2] + red[3]), 1e-12f);
    __syncthreads();
    int g8 = tid >> 7, c7 = tid & 127;
    float a = 0.f;
    if (c7 < 101)
        for (int k = g8 * 32; k < g8 * 32 + 32; ++k)
            a = fmaf(embS[k], clsw[k * 101 + c7], a);
    cP[g8][c7] = a;
    __syncthreads();
    if (g8 == 0 && c7 < 101) {
        float ssum = 0.f;
        #pragma unroll
        for (int q = 0; q < 8; ++q) ssum += cP[q][c7];
        classify[b * 101 + c7] = ssum * invS + clsb[c7];
    }
}

// -------- arnvec --------
__global__ __launch_bounds__(256) void arnvec_k(const float* __restrict__ embG,
    const float* __restrict__ arnw2, const float* __restrict__ arnb,
    float* __restrict__ arnvec)
{
    int i = blockIdx.x >> 5, b = blockIdx.x & 31, c = threadIdx.x;
    __shared__ float e[256];
    e[c] = embG[b * 256 + c];
    __syncthreads();
    const float* wp = arnw2 + (long)i * 65536;
    float a0 = arnb[i * 256 + c], a1 = 0.f;
    #pragma unroll 4
    for (int k = 0; k < 256; k += 2) {
        a0 = fmaf(e[k], wp[(long)k * 256 + c], a0);
        a1 = fmaf(e[k + 1], wp[(long)(k + 1) * 256 + c], a1);
    }
    arnvec[((long)i * 32 + b) * 256 + c] = a0 + a1;
}

// ---------------- overlap-add ----------------
__global__ __launch_bounds__(256) void ola_k(const float* __restrict__ y, float* __restrict__ out)
{
    int gidx = blockIdx.x * 256 + threadIdx.x;
    if (gidx >= 32 * 160000) return;
    int b = gidx / 160000;
    int p = gidx - b * 160000;
    int t0 = p / 160;
    int k0 = p - t0 * 160;
    const float* yb = y + (long)b * 1000 * 320;
    float v = yb[(long)t0 * 320 + k0];
    if (t0 > 0) { v += yb[(long)(t0 - 1) * 320 + k0 + 160]; v *= 0.5f; }
    out[gidx] = v;
}

extern "C" void kernel_launch(void* const* d_in, const int* in_sizes, int n_in,
                              void* d_out, int out_size, void* d_ws, size_t ws_size,
                              hipStream_t stream)
{
    (void)in_sizes; (void)n_in; (void)out_size; (void)ws_size;
    const float* input   = (const float*)d_in[0];
    const float* anchor  = (const float*)d_in[1];
    const int*   aux_len = (const int*)d_in[2];
    const float* in_w    = (const float*)d_in[4];
    const float* in_b    = (const float*)d_in[5];
    const float* out_w   = (const float*)d_in[6];
    const float* out_b   = (const float*)d_in[7];
    const float* gln_g   = (const float*)d_in[8];
    const float* gln_b   = (const float*)d_in[9];
    const float* ecapa_w = (const float*)d_in[10];
    const float* ecapa_b = (const float*)d_in[11];
    const float* att_w1  = (const float*)d_in[12];
    const float* att_b1  = (const float*)d_in[13];
    const float* attbn_g = (const float*)d_in[14];
    const float* attbn_b = (const float*)d_in[15];
    const float* att_w2  = (const float*)d_in[16];
    const float* att_b2  = (const float*)d_in[17];
    const float* bn5_g   = (const float*)d_in[18];
    const float* bn5_b   = (const float*)d_in[19];
    const float* fc6_w   = (const float*)d_in[20];
    const float* fc6_b   = (const float*)d_in[21];
    const float* bn6_g   = (const float*)d_in[22];
    const float* bn6_b   = (const float*)d_in[23];
    const float* cls_w   = (const float*)d_in[24];
    const float* cls_b   = (const float*)d_in[25];
    const float* arn_w1  = (const float*)d_in[26];
    const float* arn_w2  = (const float*)d_in[27];
    const float* arn_b   = (const float*)d_in[28];

    float* out_sig = (float*)d_out;
    float* out_cls = out_sig + (long)32 * 160000;

    // workspace layout (floats). o0b = [32000][256] bf16 = 4,096,000 floats.
    float* ws = (float*)d_ws;
    short* o0b    = (short*)ws;            // ws[0 .. 4,096,000)
    float* aux    = ws + 4096000;          // [12800,256] f32 (reused as logits)
    float* logits = aux;
    float* h      = ws + 7372800;          // [12800,256]
    float* a2     = ws + 10649600;         // [12800,256]
    float* y      = ws + 13926400;         // [32000,320] f32, ends 24,166,400
    float* glnpart = y;                    // 1024   (dead before y written)
    float* stpart  = y + 4096;             // 131072 (dead before y written)
    float* smpart  = y + 140000;           // 262144 (dead before y written)
    short* WT     = (short*)(ws + 24166400);  // 638,976 shorts = 319,488 floats
    float* smalls = ws + 24485888;
    float* meanA   = smalls;
    float* rstdA   = smalls + 32;
    float* attbias = smalls + 64;
    float* e5      = smalls + 64 + 8192;
    float* arnvec  = e5 + 16384;
    float* uArr    = arnvec + 32768;
    float* vArr    = uArr + 256;
    float* embG    = vArr + 256;

    short* WT_in  = WT;
    short* WT_ec  = WT + 81920;
    short* WT_a1  = WT + 147456;
    short* WT_a2  = WT + 212992;
    short* WT_arn = WT + 278528;
    short* WT_out = WT + 540672;

    dim3 blk(256);

    convert_wt_k<<<dim3(2496), blk, 0, stream>>>(in_w, ecapa_w, att_w1, att_w2, arn_w1, out_w, gln_g, WT);
    glnuv_k<<<dim3(1), blk, 0, stream>>>(ecapa_w, gln_g, gln_b, ecapa_b, uArr, vArr);

    mfma_gemm_k<1, 0, 1000, 1><<<dim3(2, 250), blk, 0, stream>>>(input, WT_in, in_b, o0b,
        nullptr, nullptr, nullptr, nullptr, nullptr, nullptr, 320, 256, 160000);
    mfma_gemm_k<1, 0, 400, 0><<<dim3(2, 100), blk, 0, stream>>>(anchor, WT_in, in_b, aux,
        nullptr, nullptr, nullptr, nullptr, nullptr, nullptr, 320, 256, 64000);
    gln_part_k<<<dim3(32, 16), blk, 0, stream>>>(aux, aux_len, glnpart);
    gln_comb_k<<<dim3(1), dim3(512), 0, stream>>>(glnpart, aux_len, meanA, rstdA);
    mfma_gemm_k<0, 5, 400, 0><<<dim3(2, 100), blk, 0, stream>>>(aux, WT_ec, nullptr, h,
        nullptr, uArr, vArr, meanA, rstdA, aux_len, 256, 256, 0);
    stats_part_k<<<dim3(32, 8), blk, 0, stream>>>(h, aux_len, stpart);
    stats_comb_k<<<dim3(32), blk, 0, stream>>>(stpart, aux_len, att_w1, att_b1, attbias);
    mfma_gemm_k<0, 2, 400, 0><<<dim3(2, 100), blk, 0, stream>>>(h, WT_a1, nullptr, a2,
        attbias, attbn_g, attbn_b, nullptr, nullptr, nullptr, 256, 256, 0);
    mfma_gemm_k<0, 0, 400, 0><<<dim3(2, 100), blk, 0, stream>>>(a2, WT_a2, att_b2, logits,
        nullptr, nullptr, nullptr, nullptr, nullptr, nullptr, 256, 256, 0);
    softmax_part_k<<<dim3(32, 8), blk, 0, stream>>>(logits, h, aux_len, smpart);
    softmax_comb_k<<<dim3(32), blk, 0, stream>>>(smpart, bn5_g, bn5_b, e5);
    emb_k<<<dim3(32), dim3(1024), 0, stream>>>(e5, fc6_w, fc6_b, bn6_g, bn6_b, cls_w, cls_b,
                                               out_cls, embG);
    arnvec_k<<<dim3(128), blk, 0, stream>>>(embG, arn_w2, arn_b, arnvec);
    arn_fused_k<<<dim3(500), dim3(512), 0, stream>>>(o0b, WT_arn, WT_out, out_b, arnvec, y);
    ola_k<<<dim3(20000), blk, 0, stream>>>(y, out_sig);
}